// Round 9
// baseline (719.011 us; speedup 1.0000x reference)
//
#include <hip/hip_runtime.h>
#include <hip/hip_cooperative_groups.h>
#include <math.h>

namespace cg = cooperative_groups;

// ---------------- workspace layout (float offsets) ----------------
#define WS_STATS 0         // 24 floats: [layer][S_r..S_k, Q_r..Q_k]
#define WS_W1    32        // 16*4*9   = 576      layout [s(4)][k(9)][oc(16)]
#define WS_W2    640       // 64*16*9  = 9216     layout [ic(16)][k(9)][oc(64)]
#define WS_W3    9856      // 128*64*9 = 73728    layout [ic(64)][k(9)][oc(128)]
#define WS_WFC   83584     // 2048*16  = 32768    layout [row(2048)][col(16)]
#define WS_POOL  116352    // 256*200  = 51200
#define WS_OUT1  167552    // 256*16*32*32 = 4194304
#define WS_OUT2  4361856   // 256*64*16*16 = 4194304
#define WS_OUT3  8556160   // 256*128*8*8  = 2097152

// Hamilton block table: T[a][b] -> (component, sign)
__device__ const int   d_TC[4][4] = {{0,1,2,3},{1,0,3,2},{2,3,0,1},{3,2,1,0}};
__device__ const float d_TS[4][4] = {{1.f,-1.f,-1.f,-1.f},{1.f,1.f,-1.f,1.f},
                                     {1.f,1.f,1.f,-1.f},{1.f,-1.f,1.f,1.f}};

struct Params {
    const float *x, *w_eca;
    const float *l1b, *bn1g, *bn1b;
    const float *l2b, *bn2g, *bn2b;
    const float *l3b, *bn3g, *bn3b;
    const float *fcb;
    const float *l1r, *l1i, *l1j, *l1k;
    const float *l2r, *l2i, *l2j, *l2k;
    const float *l3r, *l3i, *l3j, *l3k;
    const float *fcr, *fci, *fcj, *fck;
    float *ws, *out;
};

// ============================================================================
// Shared device helpers (bodies identical to the passing round-8 kernels)
// ============================================================================
__device__ __forceinline__ void prep_weights(const Params& P, int tid, int nthr)
{
    float* ws = P.ws;
    if (tid < 24) ws[WS_STATS + tid] = 0.f;
    { // W1: [s(4)][k(9)][oc(16)]
        const float* cp[4] = {P.l1r, P.l1i, P.l1j, P.l1k};
        for (int e = tid; e < 576; e += nthr) {
            int s = e / 144, rem = e % 144, k = rem / 16, oc = rem % 16;
            int p = oc >> 2, o = oc & 3;
            ws[WS_W1 + e] = d_TS[p][s] * cp[d_TC[p][s]][o * 9 + k];
        }
    }
    { // W2: [ic(16)][k(9)][oc(64)]
        const float* cp[4] = {P.l2r, P.l2i, P.l2j, P.l2k};
        for (int e = tid; e < 9216; e += nthr) {
            int oc = e & 63, k = (e >> 6) % 9, ic = e / 576;
            int p = oc >> 4, o = oc & 15, s = ic >> 2, ii = ic & 3;
            ws[WS_W2 + e] = d_TS[p][s] * cp[d_TC[p][s]][(o * 4 + ii) * 9 + k];
        }
    }
    { // W3: [ic(64)][k(9)][oc(128)]
        const float* cp[4] = {P.l3r, P.l3i, P.l3j, P.l3k};
        for (int e = tid; e < 73728; e += nthr) {
            int oc = e & 127, k = (e >> 7) % 9, ic = e / 1152;
            int p = oc >> 5, o = oc & 31, s = ic >> 4, ii = ic & 15;
            ws[WS_W3 + e] = d_TS[p][s] * cp[d_TC[p][s]][(o * 16 + ii) * 9 + k];
        }
    }
    { // WFC: 2048 x 16
        const float* cp[4] = {P.fcr, P.fci, P.fcj, P.fck};
        for (int e = tid; e < 32768; e += nthr) {
            int R = e >> 4, C = e & 15;
            int p = R >> 9, rr = R & 511, q = C >> 2, cc = C & 3;
            ws[WS_WFC + e] = d_TS[q][p] * cp[d_TC[q][p]][rr * 4 + cc];
        }
    }
}

__device__ __forceinline__ void mean_channels(const float* __restrict__ x,
                                              float* __restrict__ pooled,
                                              int blk, int wv, int lane)
{
    int base = blk * 50;
    for (int i = wv; i < 50; i += 4) {
        const float4* src = reinterpret_cast<const float4*>(x + (size_t)(base + i) * 1024);
        float s = 0.f;
        #pragma unroll
        for (int j = 0; j < 4; j++) {
            float4 v = src[lane + 64 * j];
            s += v.x + v.y + v.z + v.w;
        }
        #pragma unroll
        for (int off = 32; off; off >>= 1) s += __shfl_xor(s, off, 64);
        if (lane == 0) pooled[base + i] = s * (1.0f / 1024.0f);
    }
}

// per-wave top-3 of w*pooled (tie -> lowest idx); every lane gets idx0..2
__device__ __forceinline__ void top3(const float* __restrict__ pooled, float w,
                                     int b, int lane, int& idx0, int& idx1, int& idx2)
{
    float v[4]; int c[4];
    #pragma unroll
    for (int i = 0; i < 4; i++) {
        int ch = lane + 64 * i;
        c[i] = ch;
        v[i] = (ch < 200) ? w * pooled[b * 200 + ch] : -INFINITY;
    }
    idx0 = idx1 = idx2 = 0;
    for (int k = 0; k < 3; k++) {
        float bv = -INFINITY; int bi = 0x3fffffff;
        #pragma unroll
        for (int i = 0; i < 4; i++)
            if (v[i] > bv || (v[i] == bv && c[i] < bi)) { bv = v[i]; bi = c[i]; }
        for (int off = 32; off; off >>= 1) {
            float ov = __shfl_xor(bv, off, 64);
            int   oi = __shfl_xor(bi, off, 64);
            if (ov > bv || (ov == bv && oi < bi)) { bv = ov; bi = oi; }
        }
        if (k == 0) idx0 = bi; else if (k == 1) idx1 = bi; else idx2 = bi;
        #pragma unroll
        for (int i = 0; i < 4; i++) if (c[i] == bi) v[i] = -INFINITY;
    }
}

// ============================================================================
// Standalone kernels (fallback path — identical to round 8)
// ============================================================================
__global__ __launch_bounds__(256) void prepmean_kernel(Params P)
{
    const int blk = blockIdx.x, t = threadIdx.x;
    prep_weights(P, blk * 256 + t, 1024 * 256);
    mean_channels(P.x, P.ws + WS_POOL, blk, t >> 6, t & 63);
}

__global__ __launch_bounds__(256) void conv1_kernel(Params P)
{
    __shared__ float smem[3][6][36];
    __shared__ float rs[8];
    float* ws = P.ws;
    const float* pooled = ws + WS_POOL;
    int b = blockIdx.x >> 3, rg = blockIdx.x & 7;
    int t = threadIdx.x, lane = t & 63;
    if (t < 8) rs[t] = 0.f;
    int idx0, idx1, idx2;
    top3(pooled, P.w_eca[0], b, lane, idx0, idx1, idx2);
    for (int i = t; i < 648; i += 256) {
        int s = i / 216, rem = i % 216, r = rem / 36, cc = rem % 36;
        int gr = rg * 4 - 1 + r, gc = cc - 1;
        int idx = (s == 0) ? idx0 : (s == 1 ? idx1 : idx2);
        float v = 0.f;
        if (gr >= 0 && gr < 32 && gc >= 0 && gc < 32)
            v = P.x[((size_t)b * 200 + idx) * 1024 + gr * 32 + gc];
        smem[s][r][cc] = v;
    }
    __syncthreads();

    int oc = t & 15, rp = (t >> 4) & 3, ch = t >> 6;
    float bb = P.l1b[oc];
    float acc[8];
    #pragma unroll
    for (int px = 0; px < 8; px++) acc[px] = bb;

    #pragma unroll
    for (int s = 0; s < 3; s++) {
        float w[9];
        #pragma unroll
        for (int k = 0; k < 9; k++) w[k] = ws[WS_W1 + ((s + 1) * 9 + k) * 16 + oc];
        float rowv[3][12];
        #pragma unroll
        for (int dy = 0; dy < 3; dy++) {
            const float* rb = &smem[s][rp + dy][ch * 8];
            float4 a = *reinterpret_cast<const float4*>(rb);
            float4 bq = *reinterpret_cast<const float4*>(rb + 4);
            float4 cq = *reinterpret_cast<const float4*>(rb + 8);
            rowv[dy][0]=a.x;  rowv[dy][1]=a.y;  rowv[dy][2]=a.z;  rowv[dy][3]=a.w;
            rowv[dy][4]=bq.x; rowv[dy][5]=bq.y; rowv[dy][6]=bq.z; rowv[dy][7]=bq.w;
            rowv[dy][8]=cq.x; rowv[dy][9]=cq.y; rowv[dy][10]=cq.z; rowv[dy][11]=cq.w;
        }
        #pragma unroll
        for (int dy = 0; dy < 3; dy++)
            #pragma unroll
            for (int px = 0; px < 8; px++) {
                float a = acc[px];
                a = fmaf(w[dy*3+0], rowv[dy][px],   a);
                a = fmaf(w[dy*3+1], rowv[dy][px+1], a);
                a = fmaf(w[dy*3+2], rowv[dy][px+2], a);
                acc[px] = a;
            }
    }
    int row = rg * 4 + rp;
    float* outb = ws + WS_OUT1 + ((size_t)b * 16 + oc) * 1024 + row * 32 + ch * 8;
    *reinterpret_cast<float4*>(outb)     = make_float4(acc[0], acc[1], acc[2], acc[3]);
    *reinterpret_cast<float4*>(outb + 4) = make_float4(acc[4], acc[5], acc[6], acc[7]);
    float sv = 0.f, qv = 0.f;
    #pragma unroll
    for (int px = 0; px < 8; px++) { sv += acc[px]; qv += acc[px] * acc[px]; }
    int g = oc >> 2;
    atomicAdd(&rs[g], sv); atomicAdd(&rs[4 + g], qv);
    __syncthreads();
    if (t < 8) atomicAdd(&ws[WS_STATS + t], rs[t]);
}

__global__ __launch_bounds__(256) void conv2_kernel(Params P)
{
    __shared__ float smem[16][4][20];
    __shared__ float rs[8];
    __shared__ float sc[16], sh[16];
    float* ws = P.ws;
    int b = blockIdx.x >> 3, rq = blockIdx.x & 7;
    int t = threadIdx.x;
    if (t < 8) rs[t] = 0.f;
    if (t < 16) {
        const float invN = 1.0f / 1048576.0f;
        float var = 0.f;
        #pragma unroll
        for (int g = 0; g < 4; g++) {
            float S = ws[WS_STATS + g], Q = ws[WS_STATS + 4 + g];
            var += Q - S * S * invN;
        }
        var *= invN;
        float inv = 1.0f / sqrtf(var + 1e-5f);
        float scale = P.bn1g[t & 3] * inv;
        sc[t] = scale;
        sh[t] = P.bn1b[t] - ws[WS_STATS + (t >> 2)] * invN * scale;
    }
    __syncthreads();
    for (int i = t; i < 1280; i += 256) {
        int ic = i / 80, rem = i % 80, r = rem / 20, cc = rem % 20;
        int gr = rq * 2 - 1 + r, gc = cc - 1;
        float v = 0.f;
        if (gr >= 0 && gr < 16 && gc >= 0 && gc < 16) {
            const float* base = ws + WS_OUT1 + ((size_t)(b * 16 + ic) * 32 + 2 * gr) * 32 + 2 * gc;
            float2 a = *reinterpret_cast<const float2*>(base);
            float2 d = *reinterpret_cast<const float2*>(base + 32);
            float s0 = sc[ic], s1 = sh[ic];
            v = 0.25f * (fmaxf(fmaf(a.x, s0, s1), 0.f) + fmaxf(fmaf(a.y, s0, s1), 0.f)
                       + fmaxf(fmaf(d.x, s0, s1), 0.f) + fmaxf(fmaf(d.y, s0, s1), 0.f));
        }
        smem[ic][r][cc] = v;
    }
    __syncthreads();

    int oc = t & 63, rp = (t >> 6) & 1, ch = t >> 7;
    float bb = P.l2b[oc];
    float acc[8];
    #pragma unroll
    for (int px = 0; px < 8; px++) acc[px] = bb;

    const float* Wp = ws + WS_W2 + oc;
    float w[9], wn[9];
    #pragma unroll
    for (int k = 0; k < 9; k++) w[k] = Wp[k * 64];
    for (int ic = 0; ic < 16; ic++) {
        if (ic < 15) {
            #pragma unroll
            for (int k = 0; k < 9; k++) wn[k] = Wp[(ic + 1) * 576 + k * 64];
        }
        float rowv[3][12];
        #pragma unroll
        for (int dy = 0; dy < 3; dy++) {
            const float* rb = &smem[ic][rp + dy][ch * 8];
            float4 a = *reinterpret_cast<const float4*>(rb);
            float4 bq = *reinterpret_cast<const float4*>(rb + 4);
            float4 cq = *reinterpret_cast<const float4*>(rb + 8);
            rowv[dy][0]=a.x;  rowv[dy][1]=a.y;  rowv[dy][2]=a.z;  rowv[dy][3]=a.w;
            rowv[dy][4]=bq.x; rowv[dy][5]=bq.y; rowv[dy][6]=bq.z; rowv[dy][7]=bq.w;
            rowv[dy][8]=cq.x; rowv[dy][9]=cq.y; rowv[dy][10]=cq.z; rowv[dy][11]=cq.w;
        }
        #pragma unroll
        for (int dy = 0; dy < 3; dy++)
            #pragma unroll
            for (int px = 0; px < 8; px++) {
                float a = acc[px];
                a = fmaf(w[dy*3+0], rowv[dy][px],   a);
                a = fmaf(w[dy*3+1], rowv[dy][px+1], a);
                a = fmaf(w[dy*3+2], rowv[dy][px+2], a);
                acc[px] = a;
            }
        if (ic < 15) {
            #pragma unroll
            for (int k = 0; k < 9; k++) w[k] = wn[k];
        }
    }
    int row = rq * 2 + rp;
    float* outb = ws + WS_OUT2 + ((size_t)b * 64 + oc) * 256 + row * 16 + ch * 8;
    *reinterpret_cast<float4*>(outb)     = make_float4(acc[0], acc[1], acc[2], acc[3]);
    *reinterpret_cast<float4*>(outb + 4) = make_float4(acc[4], acc[5], acc[6], acc[7]);
    float sv = 0.f, qv = 0.f;
    #pragma unroll
    for (int px = 0; px < 8; px++) { sv += acc[px]; qv += acc[px] * acc[px]; }
    int g = oc >> 4;
    atomicAdd(&rs[g], sv); atomicAdd(&rs[4 + g], qv);
    __syncthreads();
    if (t < 8) atomicAdd(&ws[WS_STATS + 8 + t], rs[t]);
}

__global__ __launch_bounds__(256) void conv3_kernel(Params P)
{
    __shared__ float smem[64][4][12];
    __shared__ float rs[8];
    __shared__ float sc[64], sh[64];
    float* ws = P.ws;
    int b = blockIdx.x >> 2, rh = blockIdx.x & 3;
    int t = threadIdx.x;
    if (t < 8) rs[t] = 0.f;
    if (t < 64) {
        const float invN = 1.0f / 1048576.0f;
        float var = 0.f;
        #pragma unroll
        for (int g = 0; g < 4; g++) {
            float S = ws[WS_STATS + 8 + g], Q = ws[WS_STATS + 12 + g];
            var += Q - S * S * invN;
        }
        var *= invN;
        float inv = 1.0f / sqrtf(var + 1e-5f);
        float scale = P.bn2g[t & 15] * inv;
        sc[t] = scale;
        sh[t] = P.bn2b[t] - ws[WS_STATS + 8 + (t >> 4)] * invN * scale;
    }
    __syncthreads();
    for (int i = t; i < 3072; i += 256) {
        int ic = i / 48, rem = i % 48, r = rem / 12, cc = rem % 12;
        int gr = rh * 2 - 1 + r, gc = cc - 1;
        float v = 0.f;
        if (gr >= 0 && gr < 8 && gc >= 0 && gc < 8) {
            const float* base = ws + WS_OUT2 + ((size_t)(b * 64 + ic) * 16 + 2 * gr) * 16 + 2 * gc;
            float2 a = *reinterpret_cast<const float2*>(base);
            float2 d = *reinterpret_cast<const float2*>(base + 16);
            float s0 = sc[ic], s1 = sh[ic];
            v = 0.25f * (fmaxf(fmaf(a.x, s0, s1), 0.f) + fmaxf(fmaf(a.y, s0, s1), 0.f)
                       + fmaxf(fmaf(d.x, s0, s1), 0.f) + fmaxf(fmaf(d.y, s0, s1), 0.f));
        }
        smem[ic][r][cc] = v;
    }
    __syncthreads();

    int oc = t & 127, rp = t >> 7;
    float bb = P.l3b[oc];
    float acc[8];
    #pragma unroll
    for (int px = 0; px < 8; px++) acc[px] = bb;

    const float* Wp = ws + WS_W3 + oc;
    float w[9], wn[9];
    #pragma unroll
    for (int k = 0; k < 9; k++) w[k] = Wp[k * 128];
    for (int ic = 0; ic < 64; ic++) {
        if (ic < 63) {
            #pragma unroll
            for (int k = 0; k < 9; k++) wn[k] = Wp[(ic + 1) * 1152 + k * 128];
        }
        float rowv[3][12];
        #pragma unroll
        for (int dy = 0; dy < 3; dy++) {
            const float* rb = &smem[ic][rp + dy][0];
            float4 a = *reinterpret_cast<const float4*>(rb);
            float4 bq = *reinterpret_cast<const float4*>(rb + 4);
            float4 cq = *reinterpret_cast<const float4*>(rb + 8);
            rowv[dy][0]=a.x;  rowv[dy][1]=a.y;  rowv[dy][2]=a.z;  rowv[dy][3]=a.w;
            rowv[dy][4]=bq.x; rowv[dy][5]=bq.y; rowv[dy][6]=bq.z; rowv[dy][7]=bq.w;
            rowv[dy][8]=cq.x; rowv[dy][9]=cq.y; rowv[dy][10]=cq.z; rowv[dy][11]=cq.w;
        }
        #pragma unroll
        for (int dy = 0; dy < 3; dy++)
            #pragma unroll
            for (int px = 0; px < 8; px++) {
                float a = acc[px];
                a = fmaf(w[dy*3+0], rowv[dy][px],   a);
                a = fmaf(w[dy*3+1], rowv[dy][px+1], a);
                a = fmaf(w[dy*3+2], rowv[dy][px+2], a);
                acc[px] = a;
            }
        if (ic < 63) {
            #pragma unroll
            for (int k = 0; k < 9; k++) w[k] = wn[k];
        }
    }
    int row = rh * 2 + rp;
    float* outb = ws + WS_OUT3 + ((size_t)b * 128 + oc) * 64 + row * 8;
    *reinterpret_cast<float4*>(outb)     = make_float4(acc[0], acc[1], acc[2], acc[3]);
    *reinterpret_cast<float4*>(outb + 4) = make_float4(acc[4], acc[5], acc[6], acc[7]);
    float sv = 0.f, qv = 0.f;
    #pragma unroll
    for (int px = 0; px < 8; px++) { sv += acc[px]; qv += acc[px] * acc[px]; }
    int g = oc >> 5;
    atomicAdd(&rs[g], sv); atomicAdd(&rs[4 + g], qv);
    __syncthreads();
    if (t < 8) atomicAdd(&ws[WS_STATS + 16 + t], rs[t]);
}

__global__ __launch_bounds__(256) void fc_kernel(Params P)
{
    __shared__ float p3s[2048];
    __shared__ float sc[128], sh[128];
    __shared__ float red[256];
    float* ws = P.ws;
    int b = blockIdx.x, t = threadIdx.x;
    if (t < 128) {
        const float invN = 1.0f / 524288.0f;
        float var = 0.f;
        #pragma unroll
        for (int g = 0; g < 4; g++) {
            float S = ws[WS_STATS + 16 + g], Q = ws[WS_STATS + 20 + g];
            var += Q - S * S * invN;
        }
        var *= invN;
        float inv = 1.0f / sqrtf(var + 1e-5f);
        float scale = P.bn3g[t & 31] * inv;
        sc[t] = scale;
        sh[t] = P.bn3b[t] - ws[WS_STATS + 16 + (t >> 5)] * invN * scale;
    }
    __syncthreads();
    for (int i = t; i < 2048; i += 256) {
        int c = i >> 4, rem = i & 15, pr = rem >> 2, pc = rem & 3;
        const float* base = ws + WS_OUT3 + ((size_t)(b * 128 + c) * 8 + 2 * pr) * 8 + 2 * pc;
        float2 a = *reinterpret_cast<const float2*>(base);
        float2 d = *reinterpret_cast<const float2*>(base + 8);
        float s0 = sc[c], s1 = sh[c];
        p3s[i] = 0.25f * (fmaxf(fmaf(a.x, s0, s1), 0.f) + fmaxf(fmaf(a.y, s0, s1), 0.f)
                        + fmaxf(fmaf(d.x, s0, s1), 0.f) + fmaxf(fmaf(d.y, s0, s1), 0.f));
    }
    __syncthreads();
    int col = t & 15, fr = t >> 4;
    float s = 0.f;
    for (int i = 0; i < 128; i++) {
        int f = i * 16 + fr;
        s = fmaf(p3s[f], ws[WS_WFC + f * 16 + col], s);
    }
    red[t] = s;
    __syncthreads();
    for (int st = 128; st >= 16; st >>= 1) {
        if (t < st) red[t] += red[t + st];
        __syncthreads();
    }
    if (t < 16) P.out[b * 16 + t] = red[t] + P.fcb[t];
}

// ============================================================================
// Cooperative mega-kernel: same 5 phases with grid.sync() between them
// ============================================================================
__global__ __launch_bounds__(256, 4) void qcnet_kernel(Params P)
{
    cg::grid_group grid = cg::this_grid();
    __shared__ union {
        struct { float smem[3][6][36];  float rs[8]; } c1;
        struct { float smem[16][4][20]; float sc[16];  float sh[16];  float rs[8]; } c2;
        struct { float smem[64][4][12]; float sc[64];  float sh[64];  float rs[8]; } c3;
        struct { float p3s[2048]; float red[256]; float sc[128]; float sh[128]; } fcu;
    } U;

    const int blk = blockIdx.x, t = threadIdx.x;
    const int lane = t & 63, wv = t >> 6;
    float* ws = P.ws;

    // phase 0: weight prep + channel means
    prep_weights(P, blk * 256 + t, 1024 * 256);
    mean_channels(P.x, ws + WS_POOL, blk, wv, lane);
    grid.sync();

    // phase 1: conv1, 2 row-group units per block
    {
        int b = blk >> 2;
        int idx0, idx1, idx2;
        top3(ws + WS_POOL, P.w_eca[0], b, lane, idx0, idx1, idx2);
        for (int u = 0; u < 2; u++) {
            int rg = ((blk & 3) << 1) | u;
            if (t < 8) U.c1.rs[t] = 0.f;
            for (int i = t; i < 648; i += 256) {
                int s = i / 216, rem = i % 216, r = rem / 36, cc = rem % 36;
                int gr = rg * 4 - 1 + r, gc = cc - 1;
                int idx = (s == 0) ? idx0 : (s == 1 ? idx1 : idx2);
                float vv = 0.f;
                if (gr >= 0 && gr < 32 && gc >= 0 && gc < 32)
                    vv = P.x[((size_t)b * 200 + idx) * 1024 + gr * 32 + gc];
                U.c1.smem[s][r][cc] = vv;
            }
            __syncthreads();

            int oc = t & 15, rp = (t >> 4) & 3, ch = t >> 6;
            float bb = P.l1b[oc];
            float acc[8];
            #pragma unroll
            for (int px = 0; px < 8; px++) acc[px] = bb;

            #pragma unroll
            for (int s = 0; s < 3; s++) {
                float wk[9];
                #pragma unroll
                for (int k = 0; k < 9; k++) wk[k] = ws[WS_W1 + ((s + 1) * 9 + k) * 16 + oc];
                float rowv[3][12];
                #pragma unroll
                for (int dy = 0; dy < 3; dy++) {
                    const float* rb = &U.c1.smem[s][rp + dy][ch * 8];
                    float4 a = *reinterpret_cast<const float4*>(rb);
                    float4 bq = *reinterpret_cast<const float4*>(rb + 4);
                    float4 cq = *reinterpret_cast<const float4*>(rb + 8);
                    rowv[dy][0]=a.x;  rowv[dy][1]=a.y;  rowv[dy][2]=a.z;  rowv[dy][3]=a.w;
                    rowv[dy][4]=bq.x; rowv[dy][5]=bq.y; rowv[dy][6]=bq.z; rowv[dy][7]=bq.w;
                    rowv[dy][8]=cq.x; rowv[dy][9]=cq.y; rowv[dy][10]=cq.z; rowv[dy][11]=cq.w;
                }
                #pragma unroll
                for (int dy = 0; dy < 3; dy++)
                    #pragma unroll
                    for (int px = 0; px < 8; px++) {
                        float a = acc[px];
                        a = fmaf(wk[dy*3+0], rowv[dy][px],   a);
                        a = fmaf(wk[dy*3+1], rowv[dy][px+1], a);
                        a = fmaf(wk[dy*3+2], rowv[dy][px+2], a);
                        acc[px] = a;
                    }
            }
            int row = rg * 4 + rp;
            float* outb = ws + WS_OUT1 + ((size_t)b * 16 + oc) * 1024 + row * 32 + ch * 8;
            *reinterpret_cast<float4*>(outb)     = make_float4(acc[0], acc[1], acc[2], acc[3]);
            *reinterpret_cast<float4*>(outb + 4) = make_float4(acc[4], acc[5], acc[6], acc[7]);
            float sv = 0.f, qv = 0.f;
            #pragma unroll
            for (int px = 0; px < 8; px++) { sv += acc[px]; qv += acc[px] * acc[px]; }
            atomicAdd(&U.c1.rs[oc >> 2], sv); atomicAdd(&U.c1.rs[4 + (oc >> 2)], qv);
            __syncthreads();
            if (t < 8) atomicAdd(&ws[WS_STATS + t], U.c1.rs[t]);
            __syncthreads();
        }
    }
    grid.sync();

    // phase 2: conv2, 2 units per block
    {
        for (int u = 0; u < 2; u++) {
            int unit = blk * 2 + u;
            int b = unit >> 3, rq = unit & 7;
            if (t < 8) U.c2.rs[t] = 0.f;
            if (t < 16) {
                const float invN = 1.0f / 1048576.0f;
                float var = 0.f;
                #pragma unroll
                for (int g = 0; g < 4; g++) {
                    float S = ws[WS_STATS + g], Q = ws[WS_STATS + 4 + g];
                    var += Q - S * S * invN;
                }
                var *= invN;
                float inv = 1.0f / sqrtf(var + 1e-5f);
                float scale = P.bn1g[t & 3] * inv;
                U.c2.sc[t] = scale;
                U.c2.sh[t] = P.bn1b[t] - ws[WS_STATS + (t >> 2)] * invN * scale;
            }
            __syncthreads();
            for (int i = t; i < 1280; i += 256) {
                int ic = i / 80, rem = i % 80, r = rem / 20, cc = rem % 20;
                int gr = rq * 2 - 1 + r, gc = cc - 1;
                float vv = 0.f;
                if (gr >= 0 && gr < 16 && gc >= 0 && gc < 16) {
                    const float* base = ws + WS_OUT1 + ((size_t)(b * 16 + ic) * 32 + 2 * gr) * 32 + 2 * gc;
                    float2 a = *reinterpret_cast<const float2*>(base);
                    float2 d = *reinterpret_cast<const float2*>(base + 32);
                    float s0 = U.c2.sc[ic], s1 = U.c2.sh[ic];
                    vv = 0.25f * (fmaxf(fmaf(a.x, s0, s1), 0.f) + fmaxf(fmaf(a.y, s0, s1), 0.f)
                                + fmaxf(fmaf(d.x, s0, s1), 0.f) + fmaxf(fmaf(d.y, s0, s1), 0.f));
                }
                U.c2.smem[ic][r][cc] = vv;
            }
            __syncthreads();

            int oc = t & 63, rp = (t >> 6) & 1, ch = t >> 7;
            float bb = P.l2b[oc];
            float acc[8];
            #pragma unroll
            for (int px = 0; px < 8; px++) acc[px] = bb;

            const float* Wp = ws + WS_W2 + oc;
            float wk[9], wn[9];
            #pragma unroll
            for (int k = 0; k < 9; k++) wk[k] = Wp[k * 64];
            for (int ic = 0; ic < 16; ic++) {
                if (ic < 15) {
                    #pragma unroll
                    for (int k = 0; k < 9; k++) wn[k] = Wp[(ic + 1) * 576 + k * 64];
                }
                float rowv[3][12];
                #pragma unroll
                for (int dy = 0; dy < 3; dy++) {
                    const float* rb = &U.c2.smem[ic][rp + dy][ch * 8];
                    float4 a = *reinterpret_cast<const float4*>(rb);
                    float4 bq = *reinterpret_cast<const float4*>(rb + 4);
                    float4 cq = *reinterpret_cast<const float4*>(rb + 8);
                    rowv[dy][0]=a.x;  rowv[dy][1]=a.y;  rowv[dy][2]=a.z;  rowv[dy][3]=a.w;
                    rowv[dy][4]=bq.x; rowv[dy][5]=bq.y; rowv[dy][6]=bq.z; rowv[dy][7]=bq.w;
                    rowv[dy][8]=cq.x; rowv[dy][9]=cq.y; rowv[dy][10]=cq.z; rowv[dy][11]=cq.w;
                }
                #pragma unroll
                for (int dy = 0; dy < 3; dy++)
                    #pragma unroll
                    for (int px = 0; px < 8; px++) {
                        float a = acc[px];
                        a = fmaf(wk[dy*3+0], rowv[dy][px],   a);
                        a = fmaf(wk[dy*3+1], rowv[dy][px+1], a);
                        a = fmaf(wk[dy*3+2], rowv[dy][px+2], a);
                        acc[px] = a;
                    }
                if (ic < 15) {
                    #pragma unroll
                    for (int k = 0; k < 9; k++) wk[k] = wn[k];
                }
            }
            int row = rq * 2 + rp;
            float* outb = ws + WS_OUT2 + ((size_t)b * 64 + oc) * 256 + row * 16 + ch * 8;
            *reinterpret_cast<float4*>(outb)     = make_float4(acc[0], acc[1], acc[2], acc[3]);
            *reinterpret_cast<float4*>(outb + 4) = make_float4(acc[4], acc[5], acc[6], acc[7]);
            float sv = 0.f, qv = 0.f;
            #pragma unroll
            for (int px = 0; px < 8; px++) { sv += acc[px]; qv += acc[px] * acc[px]; }
            atomicAdd(&U.c2.rs[oc >> 4], sv); atomicAdd(&U.c2.rs[4 + (oc >> 4)], qv);
            __syncthreads();
            if (t < 8) atomicAdd(&ws[WS_STATS + 8 + t], U.c2.rs[t]);
            __syncthreads();
        }
    }
    grid.sync();

    // phase 3: conv3, 1 unit per block
    {
        int b = blk >> 2, rh = blk & 3;
        if (t < 8) U.c3.rs[t] = 0.f;
        if (t < 64) {
            const float invN = 1.0f / 1048576.0f;
            float var = 0.f;
            #pragma unroll
            for (int g = 0; g < 4; g++) {
                float S = ws[WS_STATS + 8 + g], Q = ws[WS_STATS + 12 + g];
                var += Q - S * S * invN;
            }
            var *= invN;
            float inv = 1.0f / sqrtf(var + 1e-5f);
            float scale = P.bn2g[t & 15] * inv;
            U.c3.sc[t] = scale;
            U.c3.sh[t] = P.bn2b[t] - ws[WS_STATS + 8 + (t >> 4)] * invN * scale;
        }
        __syncthreads();
        for (int i = t; i < 3072; i += 256) {
            int ic = i / 48, rem = i % 48, r = rem / 12, cc = rem % 12;
            int gr = rh * 2 - 1 + r, gc = cc - 1;
            float vv = 0.f;
            if (gr >= 0 && gr < 8 && gc >= 0 && gc < 8) {
                const float* base = ws + WS_OUT2 + ((size_t)(b * 64 + ic) * 16 + 2 * gr) * 16 + 2 * gc;
                float2 a = *reinterpret_cast<const float2*>(base);
                float2 d = *reinterpret_cast<const float2*>(base + 16);
                float s0 = U.c3.sc[ic], s1 = U.c3.sh[ic];
                vv = 0.25f * (fmaxf(fmaf(a.x, s0, s1), 0.f) + fmaxf(fmaf(a.y, s0, s1), 0.f)
                            + fmaxf(fmaf(d.x, s0, s1), 0.f) + fmaxf(fmaf(d.y, s0, s1), 0.f));
            }
            U.c3.smem[ic][r][cc] = vv;
        }
        __syncthreads();

        int oc = t & 127, rp = t >> 7;
        float bb = P.l3b[oc];
        float acc[8];
        #pragma unroll
        for (int px = 0; px < 8; px++) acc[px] = bb;

        const float* Wp = ws + WS_W3 + oc;
        float wk[9], wn[9];
        #pragma unroll
        for (int k = 0; k < 9; k++) wk[k] = Wp[k * 128];
        for (int ic = 0; ic < 64; ic++) {
            if (ic < 63) {
                #pragma unroll
                for (int k = 0; k < 9; k++) wn[k] = Wp[(ic + 1) * 1152 + k * 128];
            }
            float rowv[3][12];
            #pragma unroll
            for (int dy = 0; dy < 3; dy++) {
                const float* rb = &U.c3.smem[ic][rp + dy][0];
                float4 a = *reinterpret_cast<const float4*>(rb);
                float4 bq = *reinterpret_cast<const float4*>(rb + 4);
                float4 cq = *reinterpret_cast<const float4*>(rb + 8);
                rowv[dy][0]=a.x;  rowv[dy][1]=a.y;  rowv[dy][2]=a.z;  rowv[dy][3]=a.w;
                rowv[dy][4]=bq.x; rowv[dy][5]=bq.y; rowv[dy][6]=bq.z; rowv[dy][7]=bq.w;
                rowv[dy][8]=cq.x; rowv[dy][9]=cq.y; rowv[dy][10]=cq.z; rowv[dy][11]=cq.w;
            }
            #pragma unroll
            for (int dy = 0; dy < 3; dy++)
                #pragma unroll
                for (int px = 0; px < 8; px++) {
                    float a = acc[px];
                    a = fmaf(wk[dy*3+0], rowv[dy][px],   a);
                    a = fmaf(wk[dy*3+1], rowv[dy][px+1], a);
                    a = fmaf(wk[dy*3+2], rowv[dy][px+2], a);
                    acc[px] = a;
                }
            if (ic < 63) {
                #pragma unroll
                for (int k = 0; k < 9; k++) wk[k] = wn[k];
            }
        }
        int row = rh * 2 + rp;
        float* outb = ws + WS_OUT3 + ((size_t)b * 128 + oc) * 64 + row * 8;
        *reinterpret_cast<float4*>(outb)     = make_float4(acc[0], acc[1], acc[2], acc[3]);
        *reinterpret_cast<float4*>(outb + 4) = make_float4(acc[4], acc[5], acc[6], acc[7]);
        float sv = 0.f, qv = 0.f;
        #pragma unroll
        for (int px = 0; px < 8; px++) { sv += acc[px]; qv += acc[px] * acc[px]; }
        atomicAdd(&U.c3.rs[oc >> 5], sv); atomicAdd(&U.c3.rs[4 + (oc >> 5)], qv);
        __syncthreads();
        if (t < 8) atomicAdd(&ws[WS_STATS + 16 + t], U.c3.rs[t]);
    }
    grid.sync();

    // phase 4: fc on blocks 0..255
    if (blk < 256) {
        int b = blk;
        if (t < 128) {
            const float invN = 1.0f / 524288.0f;
            float var = 0.f;
            #pragma unroll
            for (int g = 0; g < 4; g++) {
                float S = ws[WS_STATS + 16 + g], Q = ws[WS_STATS + 20 + g];
                var += Q - S * S * invN;
            }
            var *= invN;
            float inv = 1.0f / sqrtf(var + 1e-5f);
            float scale = P.bn3g[t & 31] * inv;
            U.fcu.sc[t] = scale;
            U.fcu.sh[t] = P.bn3b[t] - ws[WS_STATS + 16 + (t >> 5)] * invN * scale;
        }
        __syncthreads();
        for (int i = t; i < 2048; i += 256) {
            int c = i >> 4, rem = i & 15, pr = rem >> 2, pc = rem & 3;
            const float* base = ws + WS_OUT3 + ((size_t)(b * 128 + c) * 8 + 2 * pr) * 8 + 2 * pc;
            float2 a = *reinterpret_cast<const float2*>(base);
            float2 d = *reinterpret_cast<const float2*>(base + 8);
            float s0 = U.fcu.sc[c], s1 = U.fcu.sh[c];
            U.fcu.p3s[i] = 0.25f * (fmaxf(fmaf(a.x, s0, s1), 0.f) + fmaxf(fmaf(a.y, s0, s1), 0.f)
                                  + fmaxf(fmaf(d.x, s0, s1), 0.f) + fmaxf(fmaf(d.y, s0, s1), 0.f));
        }
        __syncthreads();
        int col = t & 15, fr = t >> 4;
        float s = 0.f;
        for (int i = 0; i < 128; i++) {
            int f = i * 16 + fr;
            s = fmaf(U.fcu.p3s[f], ws[WS_WFC + f * 16 + col], s);
        }
        U.fcu.red[t] = s;
        __syncthreads();
        for (int st = 128; st >= 16; st >>= 1) {
            if (t < st) U.fcu.red[t] += U.fcu.red[t + st];
            __syncthreads();
        }
        if (t < 16) P.out[b * 16 + t] = U.fcu.red[t] + P.fcb[t];
    }
}

// ---------------- launch: try cooperative, fall back to 5-kernel path ----------------
extern "C" void kernel_launch(void* const* d_in, const int* in_sizes, int n_in,
                              void* d_out, int out_size, void* d_ws, size_t ws_size,
                              hipStream_t stream)
{
    (void)in_sizes; (void)n_in; (void)out_size; (void)ws_size;
    Params P;
    P.x    = (const float*)d_in[0];
    P.w_eca= (const float*)d_in[1];
    P.l1r  = (const float*)d_in[2];  P.l1i = (const float*)d_in[3];
    P.l1j  = (const float*)d_in[4];  P.l1k = (const float*)d_in[5];
    P.l1b  = (const float*)d_in[6];
    P.bn1g = (const float*)d_in[7];  P.bn1b = (const float*)d_in[8];
    P.l2r  = (const float*)d_in[9];  P.l2i = (const float*)d_in[10];
    P.l2j  = (const float*)d_in[11]; P.l2k = (const float*)d_in[12];
    P.l2b  = (const float*)d_in[13];
    P.bn2g = (const float*)d_in[14]; P.bn2b = (const float*)d_in[15];
    P.l3r  = (const float*)d_in[16]; P.l3i = (const float*)d_in[17];
    P.l3j  = (const float*)d_in[18]; P.l3k = (const float*)d_in[19];
    P.l3b  = (const float*)d_in[20];
    P.bn3g = (const float*)d_in[21]; P.bn3b = (const float*)d_in[22];
    P.fcr  = (const float*)d_in[23]; P.fci = (const float*)d_in[24];
    P.fcj  = (const float*)d_in[25]; P.fck = (const float*)d_in[26];
    P.fcb  = (const float*)d_in[27];
    P.ws   = (float*)d_ws;
    P.out  = (float*)d_out;

    void* args[] = { (void*)&P };
    hipError_t err = hipLaunchCooperativeKernel((const void*)qcnet_kernel,
                                                dim3(1024), dim3(256),
                                                args, 0, stream);
    if (err != hipSuccess) {
        (void)hipGetLastError();   // clear sticky error, use multi-kernel fallback
        prepmean_kernel<<<1024, 256, 0, stream>>>(P);
        conv1_kernel<<<2048, 256, 0, stream>>>(P);
        conv2_kernel<<<2048, 256, 0, stream>>>(P);
        conv3_kernel<<<1024, 256, 0, stream>>>(P);
        fc_kernel<<<256, 256, 0, stream>>>(P);
    }
}

// Round 10
// 181.802 us; speedup vs baseline: 3.9549x; 3.9549x over previous
//
#include <hip/hip_runtime.h>
#include <math.h>

// ---------------- workspace layout (float offsets) ----------------
#define WS_STATS 0         // 24 floats: [layer][S_r..S_k, Q_r..Q_k]
#define WS_W1    32        // 16*4*9   = 576      layout [s(4)][k(9)][oc(16)]
#define WS_W2    640       // 64*16*9  = 9216     layout [ic(16)][k(9)][oc(64)]
#define WS_W3    9856      // 128*64*9 = 73728    layout [ic(64)][k(9)][oc(128)]
#define WS_WFC   83584     // 2048*16  = 32768    layout [row(2048)][col(16)]
#define WS_POOL  116352    // 256*200  = 51200
#define WS_OUT1  167552    // 256*16*32*32 = 4194304
#define WS_OUT2  4361856   // 256*64*16*16 = 4194304
#define WS_OUT3  8556160   // 256*128*8*8  = 2097152

// Hamilton block table: T[a][b] -> (component, sign)
__device__ const int   d_TC[4][4] = {{0,1,2,3},{1,0,3,2},{2,3,0,1},{3,2,1,0}};
__device__ const float d_TS[4][4] = {{1.f,-1.f,-1.f,-1.f},{1.f,1.f,-1.f,1.f},
                                     {1.f,1.f,1.f,-1.f},{1.f,-1.f,1.f,1.f}};

// ---------------- persistent prep+mean: grid 1024, 50 channels/block ----------------
__global__ __launch_bounds__(256) void prepmean_kernel(
    const float* __restrict__ x, float* __restrict__ pooled,
    const float* l1r, const float* l1i, const float* l1j, const float* l1k,
    const float* l2r, const float* l2i, const float* l2j, const float* l2k,
    const float* l3r, const float* l3i, const float* l3j, const float* l3k,
    const float* fcr, const float* fci, const float* fcj, const float* fck,
    float* ws)
{
    const int blk = blockIdx.x, t = threadIdx.x;
    const int lane = t & 63, wv = t >> 6;
    int tid = blk * 256 + t;
    const int nthr = 1024 * 256;
    if (tid < 24) ws[WS_STATS + tid] = 0.f;

    { // W1: [s(4)][k(9)][oc(16)]
        const float* cp[4] = {l1r, l1i, l1j, l1k};
        for (int e = tid; e < 576; e += nthr) {
            int s = e / 144, rem = e % 144, k = rem / 16, oc = rem % 16;
            int p = oc >> 2, o = oc & 3;
            ws[WS_W1 + e] = d_TS[p][s] * cp[d_TC[p][s]][o * 9 + k];
        }
    }
    { // W2: [ic(16)][k(9)][oc(64)]
        const float* cp[4] = {l2r, l2i, l2j, l2k};
        for (int e = tid; e < 9216; e += nthr) {
            int oc = e & 63, k = (e >> 6) % 9, ic = e / 576;
            int p = oc >> 4, o = oc & 15, s = ic >> 2, ii = ic & 3;
            ws[WS_W2 + e] = d_TS[p][s] * cp[d_TC[p][s]][(o * 4 + ii) * 9 + k];
        }
    }
    { // W3: [ic(64)][k(9)][oc(128)]
        const float* cp[4] = {l3r, l3i, l3j, l3k};
        for (int e = tid; e < 73728; e += nthr) {
            int oc = e & 127, k = (e >> 7) % 9, ic = e / 1152;
            int p = oc >> 5, o = oc & 31, s = ic >> 4, ii = ic & 15;
            ws[WS_W3 + e] = d_TS[p][s] * cp[d_TC[p][s]][(o * 16 + ii) * 9 + k];
        }
    }
    { // WFC: 2048 x 16
        const float* cp[4] = {fcr, fci, fcj, fck};
        for (int e = tid; e < 32768; e += nthr) {
            int R = e >> 4, C = e & 15;
            int p = R >> 9, rr = R & 511, q = C >> 2, cc = C & 3;
            ws[WS_WFC + e] = d_TS[q][p] * cp[d_TC[q][p]][rr * 4 + cc];
        }
    }
    // channel means: 50 channels per block, one channel per wave-iteration
    int base = blk * 50;
    for (int i = wv; i < 50; i += 4) {
        const float4* src = reinterpret_cast<const float4*>(x + (size_t)(base + i) * 1024);
        float s = 0.f;
        #pragma unroll
        for (int j = 0; j < 4; j++) {
            float4 v = src[lane + 64 * j];
            s += v.x + v.y + v.z + v.w;
        }
        #pragma unroll
        for (int off = 32; off; off >>= 1) s += __shfl_xor(s, off, 64);
        if (lane == 0) pooled[base + i] = s * (1.0f / 1024.0f);
    }
}

// ---------------- conv1 (+in-block top-3): 4->16 ch, 32x32; grid 2048 ----
__global__ __launch_bounds__(256) void conv1_kernel(const float* __restrict__ x,
                                                    const float* __restrict__ pooled,
                                                    const float* __restrict__ w_eca,
                                                    const float* __restrict__ W1,
                                                    const float* __restrict__ b1,
                                                    float* __restrict__ out1,
                                                    float* __restrict__ stats)
{
    __shared__ float smem[3][6][36];
    __shared__ float rs[8];
    __shared__ int idx_s[3];
    int b = blockIdx.x >> 3, rg = blockIdx.x & 7;
    int t = threadIdx.x;
    if (t < 8) rs[t] = 0.f;
    if (t < 64) {
        float w = w_eca[0];
        float v[4]; int c[4];
        #pragma unroll
        for (int i = 0; i < 4; i++) {
            int ch = t + 64 * i;
            c[i] = ch;
            v[i] = (ch < 200) ? w * pooled[b * 200 + ch] : -INFINITY;
        }
        for (int k = 0; k < 3; k++) {
            float bv = -INFINITY; int bi = 0x3fffffff;
            #pragma unroll
            for (int i = 0; i < 4; i++)
                if (v[i] > bv || (v[i] == bv && c[i] < bi)) { bv = v[i]; bi = c[i]; }
            for (int off = 32; off; off >>= 1) {
                float ov = __shfl_xor(bv, off, 64);
                int   oi = __shfl_xor(bi, off, 64);
                if (ov > bv || (ov == bv && oi < bi)) { bv = ov; bi = oi; }
            }
            if (t == 0) idx_s[k] = bi;
            #pragma unroll
            for (int i = 0; i < 4; i++) if (c[i] == bi) v[i] = -INFINITY;
        }
    }
    __syncthreads();
    for (int i = t; i < 648; i += 256) {
        int s = i / 216, rem = i % 216, r = rem / 36, cc = rem % 36;
        int gr = rg * 4 - 1 + r, gc = cc - 1;
        float v = 0.f;
        if (gr >= 0 && gr < 32 && gc >= 0 && gc < 32)
            v = x[((size_t)b * 200 + idx_s[s]) * 1024 + gr * 32 + gc];
        smem[s][r][cc] = v;
    }
    __syncthreads();

    int oc = t & 15, rp = (t >> 4) & 3, ch = t >> 6;
    float bb = b1[oc];
    float acc[8];
    #pragma unroll
    for (int px = 0; px < 8; px++) acc[px] = bb;

    #pragma unroll
    for (int s = 0; s < 3; s++) {
        float w[9];
        #pragma unroll
        for (int k = 0; k < 9; k++) w[k] = W1[((s + 1) * 9 + k) * 16 + oc];
        float rowv[3][12];
        #pragma unroll
        for (int dy = 0; dy < 3; dy++) {
            const float* rb = &smem[s][rp + dy][ch * 8];
            float4 a = *reinterpret_cast<const float4*>(rb);
            float4 bq = *reinterpret_cast<const float4*>(rb + 4);
            float4 cq = *reinterpret_cast<const float4*>(rb + 8);
            rowv[dy][0]=a.x;  rowv[dy][1]=a.y;  rowv[dy][2]=a.z;  rowv[dy][3]=a.w;
            rowv[dy][4]=bq.x; rowv[dy][5]=bq.y; rowv[dy][6]=bq.z; rowv[dy][7]=bq.w;
            rowv[dy][8]=cq.x; rowv[dy][9]=cq.y; rowv[dy][10]=cq.z; rowv[dy][11]=cq.w;
        }
        #pragma unroll
        for (int dy = 0; dy < 3; dy++)
            #pragma unroll
            for (int px = 0; px < 8; px++) {
                float a = acc[px];
                a = fmaf(w[dy*3+0], rowv[dy][px],   a);
                a = fmaf(w[dy*3+1], rowv[dy][px+1], a);
                a = fmaf(w[dy*3+2], rowv[dy][px+2], a);
                acc[px] = a;
            }
    }
    int row = rg * 4 + rp;
    float* outb = out1 + ((size_t)b * 16 + oc) * 1024 + row * 32 + ch * 8;
    *reinterpret_cast<float4*>(outb)     = make_float4(acc[0], acc[1], acc[2], acc[3]);
    *reinterpret_cast<float4*>(outb + 4) = make_float4(acc[4], acc[5], acc[6], acc[7]);
    float sv = 0.f, qv = 0.f;
    #pragma unroll
    for (int px = 0; px < 8; px++) { sv += acc[px]; qv += acc[px] * acc[px]; }
    int g = oc >> 2;
    atomicAdd(&rs[g], sv); atomicAdd(&rs[4 + g], qv);
    __syncthreads();
    if (t < 8) atomicAdd(&stats[t], rs[t]);
}

// ---------------- conv2 (+fused bn1/relu/pool): 16->64 ch; grid 2048 x 128thr ----
// thread = (oc 64, rp 2): full 16-px row per thread; halved weight fetch.
__global__ __launch_bounds__(128) void conv2_kernel(const float* __restrict__ out1,
                                                    const float* __restrict__ W2,
                                                    const float* __restrict__ b2,
                                                    const float* __restrict__ bn1g,
                                                    const float* __restrict__ bn1b,
                                                    float* __restrict__ out2,
                                                    float* __restrict__ stats)
{
    __shared__ float smem[16][4][20];
    __shared__ float rs[8];
    __shared__ float sc[16], sh[16];
    int b = blockIdx.x >> 3, rq = blockIdx.x & 7;
    int t = threadIdx.x;
    if (t < 8) rs[t] = 0.f;
    if (t < 16) {
        const float invN = 1.0f / 1048576.0f;
        float var = 0.f;
        #pragma unroll
        for (int g = 0; g < 4; g++) {
            float S = stats[g], Q = stats[4 + g];
            var += Q - S * S * invN;
        }
        var *= invN;
        float inv = 1.0f / sqrtf(var + 1e-5f);
        float scale = bn1g[t & 3] * inv;
        sc[t] = scale;
        sh[t] = bn1b[t] - stats[t >> 2] * invN * scale;
    }
    __syncthreads();
    for (int i = t; i < 1280; i += 128) {
        int ic = i / 80, rem = i % 80, r = rem / 20, cc = rem % 20;
        int gr = rq * 2 - 1 + r, gc = cc - 1;
        float v = 0.f;
        if (gr >= 0 && gr < 16 && gc >= 0 && gc < 16) {
            const float* base = out1 + ((size_t)(b * 16 + ic) * 32 + 2 * gr) * 32 + 2 * gc;
            float2 a = *reinterpret_cast<const float2*>(base);
            float2 d = *reinterpret_cast<const float2*>(base + 32);
            float s0 = sc[ic], s1 = sh[ic];
            v = 0.25f * (fmaxf(fmaf(a.x, s0, s1), 0.f) + fmaxf(fmaf(a.y, s0, s1), 0.f)
                       + fmaxf(fmaf(d.x, s0, s1), 0.f) + fmaxf(fmaf(d.y, s0, s1), 0.f));
        }
        smem[ic][r][cc] = v;
    }
    __syncthreads();

    int oc = t & 63, rp = t >> 6;
    float bb = b2[oc];
    float acc[16];
    #pragma unroll
    for (int px = 0; px < 16; px++) acc[px] = bb;

    const float* Wp = W2 + oc;
    float w[9], wn[9];
    #pragma unroll
    for (int k = 0; k < 9; k++) w[k] = Wp[k * 64];
    for (int ic = 0; ic < 16; ic++) {
        if (ic < 15) {
            #pragma unroll
            for (int k = 0; k < 9; k++) wn[k] = Wp[(ic + 1) * 576 + k * 64];
        }
        float rowv[3][18];
        #pragma unroll
        for (int dy = 0; dy < 3; dy++) {
            const float* rb = &smem[ic][rp + dy][0];
            float4 a = *reinterpret_cast<const float4*>(rb);
            float4 bq = *reinterpret_cast<const float4*>(rb + 4);
            float4 cq = *reinterpret_cast<const float4*>(rb + 8);
            float4 dq = *reinterpret_cast<const float4*>(rb + 12);
            float2 e2 = *reinterpret_cast<const float2*>(rb + 16);
            rowv[dy][0]=a.x;   rowv[dy][1]=a.y;   rowv[dy][2]=a.z;   rowv[dy][3]=a.w;
            rowv[dy][4]=bq.x;  rowv[dy][5]=bq.y;  rowv[dy][6]=bq.z;  rowv[dy][7]=bq.w;
            rowv[dy][8]=cq.x;  rowv[dy][9]=cq.y;  rowv[dy][10]=cq.z; rowv[dy][11]=cq.w;
            rowv[dy][12]=dq.x; rowv[dy][13]=dq.y; rowv[dy][14]=dq.z; rowv[dy][15]=dq.w;
            rowv[dy][16]=e2.x; rowv[dy][17]=e2.y;
        }
        #pragma unroll
        for (int dy = 0; dy < 3; dy++)
            #pragma unroll
            for (int px = 0; px < 16; px++) {
                float a = acc[px];
                a = fmaf(w[dy*3+0], rowv[dy][px],   a);
                a = fmaf(w[dy*3+1], rowv[dy][px+1], a);
                a = fmaf(w[dy*3+2], rowv[dy][px+2], a);
                acc[px] = a;
            }
        if (ic < 15) {
            #pragma unroll
            for (int k = 0; k < 9; k++) w[k] = wn[k];
        }
    }
    int row = rq * 2 + rp;
    float* outb = out2 + ((size_t)b * 64 + oc) * 256 + row * 16;
    #pragma unroll
    for (int q4 = 0; q4 < 4; q4++)
        *reinterpret_cast<float4*>(outb + q4 * 4) =
            make_float4(acc[q4*4], acc[q4*4+1], acc[q4*4+2], acc[q4*4+3]);
    float sv = 0.f, qv = 0.f;
    #pragma unroll
    for (int px = 0; px < 16; px++) { sv += acc[px]; qv += acc[px] * acc[px]; }
    int g = oc >> 4;
    atomicAdd(&rs[g], sv); atomicAdd(&rs[4 + g], qv);
    __syncthreads();
    if (t < 8) atomicAdd(&stats[8 + t], rs[t]);
}

// ---------------- conv3 (+fused bn2/relu/pool): 64->128 ch; grid 1024 x 128thr ----
// thread = oc (128): 2 rows x 8 px per thread; halved weight fetch.
__global__ __launch_bounds__(128) void conv3_kernel(const float* __restrict__ out2,
                                                    const float* __restrict__ W3,
                                                    const float* __restrict__ b3,
                                                    const float* __restrict__ bn2g,
                                                    const float* __restrict__ bn2b,
                                                    float* __restrict__ out3,
                                                    float* __restrict__ stats)
{
    __shared__ float smem[64][4][12];
    __shared__ float rs[8];
    __shared__ float sc[64], sh[64];
    int b = blockIdx.x >> 2, rh = blockIdx.x & 3;
    int t = threadIdx.x;
    if (t < 8) rs[t] = 0.f;
    if (t < 64) {
        const float invN = 1.0f / 1048576.0f;
        float var = 0.f;
        #pragma unroll
        for (int g = 0; g < 4; g++) {
            float S = stats[8 + g], Q = stats[12 + g];
            var += Q - S * S * invN;
        }
        var *= invN;
        float inv = 1.0f / sqrtf(var + 1e-5f);
        float scale = bn2g[t & 15] * inv;
        sc[t] = scale;
        sh[t] = bn2b[t] - stats[8 + (t >> 4)] * invN * scale;
    }
    __syncthreads();
    for (int i = t; i < 3072; i += 128) {
        int ic = i / 48, rem = i % 48, r = rem / 12, cc = rem % 12;
        int gr = rh * 2 - 1 + r, gc = cc - 1;
        float v = 0.f;
        if (gr >= 0 && gr < 8 && gc >= 0 && gc < 8) {
            const float* base = out2 + ((size_t)(b * 64 + ic) * 16 + 2 * gr) * 16 + 2 * gc;
            float2 a = *reinterpret_cast<const float2*>(base);
            float2 d = *reinterpret_cast<const float2*>(base + 16);
            float s0 = sc[ic], s1 = sh[ic];
            v = 0.25f * (fmaxf(fmaf(a.x, s0, s1), 0.f) + fmaxf(fmaf(a.y, s0, s1), 0.f)
                       + fmaxf(fmaf(d.x, s0, s1), 0.f) + fmaxf(fmaf(d.y, s0, s1), 0.f));
        }
        smem[ic][r][cc] = v;
    }
    __syncthreads();

    int oc = t;   // 128 threads = 128 oc
    float bb = b3[oc];
    float acc[16];
    #pragma unroll
    for (int px = 0; px < 16; px++) acc[px] = bb;

    const float* Wp = W3 + oc;
    float w[9], wn[9];
    #pragma unroll
    for (int k = 0; k < 9; k++) w[k] = Wp[k * 128];
    for (int ic = 0; ic < 64; ic++) {
        if (ic < 63) {
            #pragma unroll
            for (int k = 0; k < 9; k++) wn[k] = Wp[(ic + 1) * 1152 + k * 128];
        }
        float rowv[4][12];
        #pragma unroll
        for (int r = 0; r < 4; r++) {
            const float* rb = &smem[ic][r][0];
            float4 a = *reinterpret_cast<const float4*>(rb);
            float4 bq = *reinterpret_cast<const float4*>(rb + 4);
            float4 cq = *reinterpret_cast<const float4*>(rb + 8);
            rowv[r][0]=a.x;  rowv[r][1]=a.y;  rowv[r][2]=a.z;  rowv[r][3]=a.w;
            rowv[r][4]=bq.x; rowv[r][5]=bq.y; rowv[r][6]=bq.z; rowv[r][7]=bq.w;
            rowv[r][8]=cq.x; rowv[r][9]=cq.y; rowv[r][10]=cq.z; rowv[r][11]=cq.w;
        }
        #pragma unroll
        for (int orow = 0; orow < 2; orow++)
            #pragma unroll
            for (int dy = 0; dy < 3; dy++)
                #pragma unroll
                for (int px = 0; px < 8; px++) {
                    float a = acc[orow * 8 + px];
                    a = fmaf(w[dy*3+0], rowv[orow + dy][px],   a);
                    a = fmaf(w[dy*3+1], rowv[orow + dy][px+1], a);
                    a = fmaf(w[dy*3+2], rowv[orow + dy][px+2], a);
                    acc[orow * 8 + px] = a;
                }
        if (ic < 63) {
            #pragma unroll
            for (int k = 0; k < 9; k++) w[k] = wn[k];
        }
    }
    float* outb = out3 + ((size_t)b * 128 + oc) * 64 + rh * 16;
    #pragma unroll
    for (int q4 = 0; q4 < 4; q4++)
        *reinterpret_cast<float4*>(outb + q4 * 4) =
            make_float4(acc[q4*4], acc[q4*4+1], acc[q4*4+2], acc[q4*4+3]);
    float sv = 0.f, qv = 0.f;
    #pragma unroll
    for (int px = 0; px < 16; px++) { sv += acc[px]; qv += acc[px] * acc[px]; }
    int g = oc >> 5;
    atomicAdd(&rs[g], sv); atomicAdd(&rs[4 + g], qv);
    __syncthreads();
    if (t < 8) atomicAdd(&stats[16 + t], rs[t]);
}

// ---------------- fc (+fused bn3/relu/pool staging): [256,2048]@[2048,16]+b ----
__global__ __launch_bounds__(256) void fc_kernel(const float* __restrict__ out3,
                                                 const float* __restrict__ WFC,
                                                 const float* __restrict__ fcb,
                                                 const float* __restrict__ bn3g,
                                                 const float* __restrict__ bn3b,
                                                 const float* __restrict__ stats,
                                                 float* __restrict__ out)
{
    __shared__ float p3s[2048];
    __shared__ float sc[128], sh[128];
    __shared__ float red[256];
    int b = blockIdx.x, t = threadIdx.x;
    if (t < 128) {
        const float invN = 1.0f / 524288.0f;
        float var = 0.f;
        #pragma unroll
        for (int g = 0; g < 4; g++) {
            float S = stats[16 + g], Q = stats[20 + g];
            var += Q - S * S * invN;
        }
        var *= invN;
        float inv = 1.0f / sqrtf(var + 1e-5f);
        float scale = bn3g[t & 31] * inv;
        sc[t] = scale;
        sh[t] = bn3b[t] - stats[16 + (t >> 5)] * invN * scale;
    }
    __syncthreads();
    for (int i = t; i < 2048; i += 256) {
        int c = i >> 4, rem = i & 15, pr = rem >> 2, pc = rem & 3;
        const float* base = out3 + ((size_t)(b * 128 + c) * 8 + 2 * pr) * 8 + 2 * pc;
        float2 a = *reinterpret_cast<const float2*>(base);
        float2 d = *reinterpret_cast<const float2*>(base + 8);
        float s0 = sc[c], s1 = sh[c];
        p3s[i] = 0.25f * (fmaxf(fmaf(a.x, s0, s1), 0.f) + fmaxf(fmaf(a.y, s0, s1), 0.f)
                        + fmaxf(fmaf(d.x, s0, s1), 0.f) + fmaxf(fmaf(d.y, s0, s1), 0.f));
    }
    __syncthreads();
    int col = t & 15, fr = t >> 4;
    float s = 0.f;
    for (int i = 0; i < 128; i++) {
        int f = i * 16 + fr;
        s = fmaf(p3s[f], WFC[f * 16 + col], s);
    }
    red[t] = s;
    __syncthreads();
    for (int st = 128; st >= 16; st >>= 1) {
        if (t < st) red[t] += red[t + st];
        __syncthreads();
    }
    if (t < 16) out[b * 16 + t] = red[t] + fcb[t];
}

// ---------------- launch ----------------
extern "C" void kernel_launch(void* const* d_in, const int* in_sizes, int n_in,
                              void* d_out, int out_size, void* d_ws, size_t ws_size,
                              hipStream_t stream)
{
    (void)in_sizes; (void)n_in; (void)out_size; (void)ws_size;
    const float* x     = (const float*)d_in[0];
    const float* w_eca = (const float*)d_in[1];
    const float* l1r = (const float*)d_in[2],  *l1i = (const float*)d_in[3];
    const float* l1j = (const float*)d_in[4],  *l1k = (const float*)d_in[5];
    const float* l1b = (const float*)d_in[6];
    const float* bn1g = (const float*)d_in[7], *bn1b = (const float*)d_in[8];
    const float* l2r = (const float*)d_in[9],  *l2i = (const float*)d_in[10];
    const float* l2j = (const float*)d_in[11], *l2k = (const float*)d_in[12];
    const float* l2b = (const float*)d_in[13];
    const float* bn2g = (const float*)d_in[14], *bn2b = (const float*)d_in[15];
    const float* l3r = (const float*)d_in[16], *l3i = (const float*)d_in[17];
    const float* l3j = (const float*)d_in[18], *l3k = (const float*)d_in[19];
    const float* l3b = (const float*)d_in[20];
    const float* bn3g = (const float*)d_in[21], *bn3b = (const float*)d_in[22];
    const float* fcr = (const float*)d_in[23], *fci = (const float*)d_in[24];
    const float* fcj = (const float*)d_in[25], *fck = (const float*)d_in[26];
    const float* fcb = (const float*)d_in[27];

    float* ws   = (float*)d_ws;
    float* outp = (float*)d_out;

    prepmean_kernel<<<1024, 256, 0, stream>>>(x, ws + WS_POOL,
        l1r, l1i, l1j, l1k, l2r, l2i, l2j, l2k, l3r, l3i, l3j, l3k,
        fcr, fci, fcj, fck, ws);
    conv1_kernel<<<2048, 256, 0, stream>>>(x, ws + WS_POOL, w_eca, ws + WS_W1,
                                           l1b, ws + WS_OUT1, ws + WS_STATS);
    conv2_kernel<<<2048, 128, 0, stream>>>(ws + WS_OUT1, ws + WS_W2, l2b, bn1g, bn1b,
                                           ws + WS_OUT2, ws + WS_STATS);
    conv3_kernel<<<1024, 128, 0, stream>>>(ws + WS_OUT2, ws + WS_W3, l3b, bn2g, bn2b,
                                           ws + WS_OUT3, ws + WS_STATS);
    fc_kernel<<<256, 256, 0, stream>>>(ws + WS_OUT3, ws + WS_WFC, fcb, bn3g, bn3b,
                                       ws + WS_STATS, outp);
}